// Round 9
// baseline (441.169 us; speedup 1.0000x reference)
//
#include <hip/hip_runtime.h>
#include <math.h>

#define HH 512
#define WW 512
#define NPIX (HH*WW)
#define NB 32
#define NS 21           // 2*MS+1 shifts per axis
#define KWIN 492        // window size (H - 2*10)

typedef __attribute__((ext_vector_type(8))) short short8;
typedef __attribute__((ext_vector_type(8))) unsigned short ushort8;
typedef __attribute__((ext_vector_type(4))) float floatx4;

__device__ __forceinline__ unsigned short f2bf(float f) {
    unsigned u = __float_as_uint(f);
    unsigned r = (u + 0x7fffu + ((u >> 16) & 1u)) >> 16;
    return (unsigned short)r;
}

// ---------------- Kernel W1a: interior column sums + template sums ----------
__global__ __launch_bounds__(256) void colsum_phase1(
    const float* __restrict__ fr, const float* __restrict__ tpl,
    float* __restrict__ I1, float* __restrict__ I2,
    double* __restrict__ sum1, double* __restrict__ sum2)
{
    int blk = blockIdx.x;
    int t   = threadIdx.x;
    if (blk < 256) {
        int b  = blk >> 3;
        int yg = blk & 7;
        int y0 = 20 + 59 * yg;
        const float* img = fr + (size_t)b * NPIX;
        int xa = t, xb = t + 256;
        float s1a = 0.f, s2a = 0.f, s1b = 0.f, s2b = 0.f;
        for (int y = y0; y < y0 + 59; ++y) {
            float va = img[(size_t)y * WW + xa];
            float vb = img[(size_t)y * WW + xb];
            s1a += va; s2a += va * va;
            s1b += vb; s2b += vb * vb;
        }
        atomicAdd(&I1[b * WW + xa], s1a); atomicAdd(&I2[b * WW + xa], s2a);
        atomicAdd(&I1[b * WW + xb], s1b); atomicAdd(&I2[b * WW + xb], s2b);
    } else {
        int gq = blk - 256;            // rows [64gq, 64gq+64)
        int y0 = 64 * gq;
        int xa = t, xb = t + 256;
        float s1a = 0.f, s2a = 0.f, s1b = 0.f, s2b = 0.f;
        for (int y = y0; y < y0 + 64; ++y) {
            float va = tpl[(size_t)y * WW + xa];
            float vb = tpl[(size_t)y * WW + xb];
            s1a += va; s2a += va * va;
            s1b += vb; s2b += vb * vb;
        }
        double d1 = (double)s1a + (double)s1b;
        double d2 = (double)s2a + (double)s2b;
        for (int off = 32; off; off >>= 1) {
            d1 += __shfl_down(d1, off);
            d2 += __shfl_down(d2, off);
        }
        __shared__ double r1[4], r2[4];
        int lane = t & 63, wv = t >> 6;
        if (lane == 0) { r1[wv] = d1; r2[wv] = d2; }
        __syncthreads();
        if (t == 0) {
            atomicAdd(&sum1[32], r1[0] + r1[1] + r1[2] + r1[3]);
            atomicAdd(&sum2[32], r2[0] + r2[1] + r2[2] + r2[3]);
        }
    }
}

// ---------------- Kernel W1b: edges + sliding windows + frame totals --------
__global__ __launch_bounds__(512) void colsum_combine(
    const float* __restrict__ fr, const float* __restrict__ I1,
    const float* __restrict__ I2, float* __restrict__ cs1,
    float* __restrict__ cs2, double* __restrict__ sum1)
{
    int b = blockIdx.x;
    int x = threadIdx.x;
    const float* img = fr + (size_t)b * NPIX;
    float top[20], bot[20];
#pragma unroll
    for (int y = 0; y < 20; ++y) top[y] = img[(size_t)y * WW + x];
#pragma unroll
    for (int y = 0; y < 20; ++y) bot[y] = img[(size_t)(492 + y) * WW + x];

    float t1 = 0.f, t2 = 0.f, b1 = 0.f, b2 = 0.f;
#pragma unroll
    for (int y = 0; y < 20; ++y) {
        t1 += top[y]; t2 += top[y] * top[y];
        b1 += bot[y]; b2 += bot[y] * bot[y];
    }
    float i1 = I1[b * WW + x], i2 = I2[b * WW + x];

    double tot = (double)i1 + (double)t1 + (double)b1;
    for (int off = 32; off; off >>= 1) tot += __shfl_down(tot, off);
    __shared__ double red[8];
    int lane = x & 63, wv = x >> 6;
    if (lane == 0) red[wv] = tot;
    __syncthreads();
    if (x == 0) {
        double s = 0.0;
        for (int i = 0; i < 8; ++i) s += red[i];
        sum1[b] = s;
    }

    float s1 = i1 + t1, s2 = i2 + t2;
    size_t base = (size_t)b * NS * WW + x;
    cs1[base] = s1; cs2[base] = s2;
#pragma unroll
    for (int u = 1; u < NS; ++u) {
        float a = top[u-1], c = bot[u-1];
        s1 += c - a;
        s2 += c * c - a * a;
        cs1[base + (size_t)u * WW] = s1;
        cs2[base + (size_t)u * WW] = s2;
    }
}

// ---------------- Kernel W2: window sums -> denominator (wave per triple) ---
__global__ __launch_bounds__(256) void denom_kernel(
    const float* __restrict__ cs1, const float* __restrict__ cs2,
    const double* __restrict__ sum1, const double* __restrict__ sum2,
    float* __restrict__ denom)
{
    int wid  = blockIdx.x * 4 + (threadIdx.x >> 6);   // one wave per (b,u,v)
    int lane = threadIdx.x & 63;
    if (wid >= NB * NS * NS) return;
    int v  = wid % NS;
    int bu = wid / NS;
    const float* r1 = cs1 + (size_t)bu * WW + v;
    const float* r2 = cs2 + (size_t)bu * WW + v;
    double s1 = 0.0, s2 = 0.0;
    for (int x = lane; x < KWIN; x += 64) { s1 += (double)r1[x]; s2 += (double)r2[x]; }
    for (int off = 32; off; off >>= 1) {
        s1 += __shfl_down(s1, off);
        s2 += __shfl_down(s2, off);
    }
    if (lane == 0) {
        const double inv = 1.0 / ((double)KWIN * (double)KWIN);
        double m1 = s1 * inv, m2 = s2 * inv;
        double var = m2 - (m1 * m1) * inv + 1e-8;   // reference's formula
        if (var < 0.0) var = 0.0;
        double tv = sum2[32] - sum1[32] * sum1[32] * (1.0 / (double)NPIX) + 1e-8;
        denom[wid] = (float)sqrt(tv * var);
    }
}

// ---------------- Prep: frames fp32 -> bf16 interleaved (LDS transpose)
//                  + 21 dv-shifted bf16 template copies -----------------------
// blocks [0,512):    conv: block = 64 kc8-octets x 32 frames (coalesced both ways)
// blocks [512,1226): tplv: dv = blk2/34, 16 pr-rows
__global__ __launch_bounds__(256) void prep_kernel(
    const float* __restrict__ fr, const float* __restrict__ tpl,
    unsigned short* __restrict__ frBi, unsigned short* __restrict__ tplv)
{
    int blk = blockIdx.x;
    if (blk < 512) {
        int kbase   = blk * 512;        // k range [kbase, kbase+512)
        int kc8base = blk * 64;
        __shared__ unsigned short tile[64][264];   // [kc8][n*8+j], row pad 8 shorts
        int half = threadIdx.x >> 7;    // 0,1
        int tq   = threadIdx.x & 127;   // float4 index within a frame row
        int kc8l = tq >> 1;
        int j4   = (tq & 1) * 4;
#pragma unroll
        for (int n2 = 0; n2 < 32; n2 += 2) {
            int n = n2 + half;
            const float* src = fr + (size_t)n * NPIX + kbase + tq * 4;
            float4 v = *(const float4*)src;
            unsigned short* d = &tile[kc8l][n * 8 + j4];
            d[0] = f2bf(v.x); d[1] = f2bf(v.y); d[2] = f2bf(v.z); d[3] = f2bf(v.w);
        }
        __syncthreads();
        for (int c = threadIdx.x; c < 2048; c += 256) {
            int kl = c >> 5;
            int n  = c & 31;
            ushort8 o = *(ushort8*)&tile[kl][n * 8];
            *(ushort8*)(frBi + ((size_t)(kc8base + kl) * 32 + n) * 8) = o;
        }
    } else {
        int blk2 = blk - 512;           // 0..713
        int dv   = blk2 / 34;
        int prg  = blk2 % 34;
        int prEnd = min(16 * prg + 16, 532);
        for (int pr = 16 * prg; pr < prEnd; ++pr) {
            int sy = (pr + 502) & 511;  // (pr-10) mod 512
            const float* srow = tpl + (size_t)sy * WW;
            unsigned short* drow = tplv + ((size_t)dv * 532 + pr) * 512;
            for (int x = threadIdx.x; x < 512; x += 256) {
                int sx = (x - dv + 522) & 511;   // (x - dv + 10) mod 512
                drow[x] = f2bf(srow[sx]);
            }
        }
    }
}

// ---------------- Kernel C: implicit-GEMM correlation via MFMA --------------
// C[m=(du,dv)][n=b] = sum_k T[(du,dv)][k] * I[k][b]; M=441, N=32, K=262144.
// Block = 896 thr = 14 waves = ALL m-groups sharing ONE k-chunk (512 k):
// identical co-timed B stream -> L1/L2-local, no cross-CU refetch.
// Grid = 512 k-chunks = 2 blocks/CU = 28 waves/CU.
__global__ __launch_bounds__(896) void corr_mfma(
    const unsigned short* __restrict__ frBi,
    const unsigned short* __restrict__ tplv,
    float* __restrict__ cc)
{
    const int l   = threadIdx.x & 63;
    const int mg2 = threadIdx.x >> 6;      // wave 0..13 = m-pair group
    const int k0  = blockIdx.x << 9;       // k-chunk base (512 each)
    const int kg  = l >> 4;                // k-group 0..3
    const int ln  = l & 15;

    const unsigned short* pA[2];
#pragma unroll
    for (int mt = 0; mt < 2; ++mt) {
        int m_g = 32 * mg2 + 16 * mt + ln;
        int du  = (m_g * 1561) >> 15;      // m_g/21 exact for m_g<=447
        int dv  = m_g - 21 * du;
        if (m_g >= 441) { du = 0; dv = 0; }   // pad rows: loaded, never stored
        pA[mt] = tplv + ((size_t)(dv * 532 + 20 - du) * 512 + 8 * kg + k0);
    }
    const unsigned short* pB0 = frBi + ((size_t)k0 * 32 + kg * 256 + ln * 8);
    const unsigned short* pB1 = pB0 + 128;   // frames 16..31

    floatx4 acc00 = {}, acc01 = {}, acc10 = {}, acc11 = {};

#pragma unroll
    for (int ks = 0; ks < 16; ++ks) {      // 16 steps x 32 k = 512
        short8 A0 = *(const short8*)pA[0];
        short8 A1 = *(const short8*)pA[1];
        short8 B0 = *(const short8*)pB0;
        short8 B1 = *(const short8*)pB1;
        acc00 = __builtin_amdgcn_mfma_f32_16x16x32_bf16(A0, B0, acc00, 0, 0, 0);
        acc01 = __builtin_amdgcn_mfma_f32_16x16x32_bf16(A0, B1, acc01, 0, 0, 0);
        acc10 = __builtin_amdgcn_mfma_f32_16x16x32_bf16(A1, B0, acc10, 0, 0, 0);
        acc11 = __builtin_amdgcn_mfma_f32_16x16x32_bf16(A1, B1, acc11, 0, 0, 0);
        pA[0] += 32; pA[1] += 32; pB0 += 1024; pB1 += 1024;
    }

    // C/D layout: col n = lane&15, row m = 4*(lane>>4)+reg (HW-verified)
#pragma unroll
    for (int r = 0; r < 4; ++r) {
        int mrow = 4 * kg + r;
        int m0 = 32 * mg2 + mrow;          // mt=0 (always < 441)
        int m1 = m0 + 16;                  // mt=1
        int nA  = ln;
        int nBn = ln + 16;
        atomicAdd(&cc[(size_t)nA  * 441 + m0], acc00[r]);
        atomicAdd(&cc[(size_t)nBn * 441 + m0], acc01[r]);
        if (m1 < 441) {
            atomicAdd(&cc[(size_t)nA  * 441 + m1], acc10[r]);
            atomicAdd(&cc[(size_t)nBn * 441 + m1], acc11[r]);
        }
    }
}

// ---------------- Kernel S: argmax + log-parabola subpixel ------------------
__global__ __launch_bounds__(64) void argmax_kernel(
    const float* __restrict__ cc, const float* __restrict__ denom,
    const double* __restrict__ sum1, float* __restrict__ shifts)
{
    int b = blockIdx.x;
    const float* C = cc    + (size_t)b * NS * NS;
    const float* D = denom + (size_t)b * NS * NS;
    float corr = (float)(sum1[b] * sum1[32] * (1.0 / (double)NPIX));
    int l = threadIdx.x;
    float best = -1e30f; int bidx = NS * NS;
    for (int i = l; i < NS * NS; i += 64) {
        float v = fabsf(C[i] - corr) / D[i];
        if (v != v) v = 0.f;               // NaN -> 0 (matches reference)
        if (v > best) { best = v; bidx = i; }
    }
    for (int off = 32; off; off >>= 1) {
        float ov = __shfl_down(best, off);
        int   oi = __shfl_down(bidx, off);
        if (ov > best || (ov == best && oi < bidx)) { best = ov; bidx = oi; }
    }
    if (l == 0) {
        int shx = bidx / NS, shy = bidx % NS;
        auto nccAt = [&](int i, int j) -> float {
            i = (i < 0) ? i + NS : i; i = (i > NS - 1) ? NS - 1 : i;  // jnp wrap-then-clamp
            j = (j < 0) ? j + NS : j; j = (j > NS - 1) ? NS - 1 : j;
            float v = fabsf(C[i * NS + j] - corr) / D[i * NS + j];
            if (v != v) v = 0.f;
            return v;
        };
        float lc  = logf(nccAt(shx, shy));
        float lxm = logf(nccAt(shx - 1, shy));
        float lxp = logf(nccAt(shx + 1, shy));
        float lym = logf(nccAt(shx, shy - 1));
        float lyp = logf(nccAt(shx, shy + 1));
        float shxn = -(float)(shx - 10) - (lxm - lxp) / (2.f * lxm - 4.f * lc + 2.f * lxp);
        float shyn = -(float)(shy - 10) - (lym - lyp) / (2.f * lym - 4.f * lc + 2.f * lyp);
        shifts[b]      = shxn;   // dy
        shifts[32 + b] = shyn;   // dx
    }
}

// ---------------- Kernel B: bilinear warp + transposed write ----------------
__device__ __forceinline__ float samp(const float* __restrict__ img, int y, int x) {
    bool valid = (y >= 0) & (y < HH) & (x >= 0) & (x < WW);
    int yc = min(max(y, 0), HH - 1), xc = min(max(x, 0), WW - 1);
    float v = img[(size_t)yc * WW + xc];
    return valid ? v : 0.f;
}

__global__ __launch_bounds__(256) void warp_kernel(
    const float* __restrict__ fr, const float* __restrict__ shifts,
    float* __restrict__ out)
{
    int b  = blockIdx.z;
    int h0 = blockIdx.y * 32;
    int w0 = blockIdx.x * 32;
    float dy = shifts[b], dx = shifts[32 + b];
    const float* img = fr + (size_t)b * NPIX;
    __shared__ float tile[32][33];
    int tx = threadIdx.x & 31;
    int tz = threadIdx.x >> 5;
#pragma unroll
    for (int s = 0; s < 4; ++s) {
        int h = h0 + tz + 8 * s;
        int w = w0 + tx;
        float yq = (float)h - dy;
        float xq = (float)w - dx;
        float y0f = floorf(yq), x0f = floorf(xq);
        float wy = yq - y0f, wx = xq - x0f;
        int y0 = (int)y0f, x0 = (int)x0f;
        float v00 = samp(img, y0,     x0);
        float v01 = samp(img, y0,     x0 + 1);
        float v10 = samp(img, y0 + 1, x0);
        float v11 = samp(img, y0 + 1, x0 + 1);
        float val = v00 * (1.f - wy) * (1.f - wx) + v01 * (1.f - wy) * wx
                  + v10 * wy * (1.f - wx)         + v11 * wy * wx;
        tile[tz + 8 * s][tx] = val;
    }
    __syncthreads();
#pragma unroll
    for (int s = 0; s < 4; ++s) {
        int hh = tx;
        int ww = tz + 8 * s;
        out[(size_t)b * NPIX + (size_t)(w0 + ww) * HH + (h0 + hh)] = tile[hh][ww];
    }
}

// ---------------- launch ----------------------------------------------------
extern "C" void kernel_launch(void* const* d_in, const int* in_sizes, int n_in,
                              void* d_out, int out_size, void* d_ws, size_t ws_size,
                              hipStream_t stream) {
    const float* fr  = (const float*)d_in[0];   // (1,32,512,512,1) flat
    const float* tpl = (const float*)d_in[1];   // (512,512)
    float* out = (float*)d_out;
    char* ws = (char*)d_ws;

    // ws layout (~28.5 MB). frBi OVERLAYS cs1/cs2 (consumed by denom first).
    double* sum1    = (double*)(ws + 0);          // 33 doubles
    double* sum2    = (double*)(ws + 512);        // 33 doubles
    float*  cc      = (float*) (ws + 4096);       // 32*441 floats
    float*  I1      = (float*) (ws + 61440);      // 32*512 floats
    float*  I2      = (float*) (ws + 126976);     // 32*512 floats
    float*  shifts  = (float*) (ws + 196608);     // 64 floats
    float*  denom   = (float*) (ws + 200704);     // 32*441 floats
    float*  cs1     = (float*) (ws + 262144);     // 32*21*512 floats
    float*  cs2     = (float*) (ws + 1638400);    // 32*21*512 floats
    unsigned short* frBi = (unsigned short*)(ws + 262144);    // 16.78 MB (after denom)
    unsigned short* tplv = (unsigned short*)(ws + 17039360);  // 11.44 MB

    hipMemsetAsync(ws, 0, 192512, stream);       // zero sums + cc + I1/I2

    colsum_phase1 <<<264, 256, 0, stream>>>(fr, tpl, I1, I2, sum1, sum2);
    colsum_combine<<<32, 512, 0, stream>>>(fr, I1, I2, cs1, cs2, sum1);
    denom_kernel  <<<(NB * NS * NS + 3) / 4, 256, 0, stream>>>(cs1, cs2, sum1, sum2, denom);
    // prep AFTER denom (frBi overlays cs1/cs2)
    prep_kernel   <<<1226, 256, 0, stream>>>(fr, tpl, frBi, tplv);
    corr_mfma     <<<512, 896, 0, stream>>>(frBi, tplv, cc);
    argmax_kernel <<<32, 64, 0, stream>>>(cc, denom, sum1, shifts);
    warp_kernel   <<<dim3(16, 16, 32), 256, 0, stream>>>(fr, shifts, out);
}

// Round 10
// 201.324 us; speedup vs baseline: 2.1913x; 2.1913x over previous
//
#include <hip/hip_runtime.h>
#include <math.h>

#define HH 512
#define WW 512
#define NPIX (HH*WW)
#define NB 32
#define NS 21           // 2*MS+1 shifts per axis
#define KWIN 492        // window size (H - 2*10)
#define NKB 512         // split-K chunks
#define MT28 28         // m-tiles (448 = 28*16, M=441 padded)

typedef __attribute__((ext_vector_type(8))) short short8;
typedef __attribute__((ext_vector_type(8))) unsigned short ushort8;
typedef __attribute__((ext_vector_type(4))) float floatx4;

__device__ __forceinline__ unsigned short f2bf(float f) {
    unsigned u = __float_as_uint(f);
    unsigned r = (u + 0x7fffu + ((u >> 16) & 1u)) >> 16;
    return (unsigned short)r;
}

// ---------------- Kernel W1a: interior column sums + template sums ----------
__global__ __launch_bounds__(256) void colsum_phase1(
    const float* __restrict__ fr, const float* __restrict__ tpl,
    float* __restrict__ I1, float* __restrict__ I2,
    double* __restrict__ sum1, double* __restrict__ sum2)
{
    int blk = blockIdx.x;
    int t   = threadIdx.x;
    if (blk < 256) {
        int b  = blk >> 3;
        int yg = blk & 7;
        int y0 = 20 + 59 * yg;
        const float* img = fr + (size_t)b * NPIX;
        int xa = t, xb = t + 256;
        float s1a = 0.f, s2a = 0.f, s1b = 0.f, s2b = 0.f;
        for (int y = y0; y < y0 + 59; ++y) {
            float va = img[(size_t)y * WW + xa];
            float vb = img[(size_t)y * WW + xb];
            s1a += va; s2a += va * va;
            s1b += vb; s2b += vb * vb;
        }
        atomicAdd(&I1[b * WW + xa], s1a); atomicAdd(&I2[b * WW + xa], s2a);
        atomicAdd(&I1[b * WW + xb], s1b); atomicAdd(&I2[b * WW + xb], s2b);
    } else {
        int gq = blk - 256;            // rows [64gq, 64gq+64)
        int y0 = 64 * gq;
        int xa = t, xb = t + 256;
        float s1a = 0.f, s2a = 0.f, s1b = 0.f, s2b = 0.f;
        for (int y = y0; y < y0 + 64; ++y) {
            float va = tpl[(size_t)y * WW + xa];
            float vb = tpl[(size_t)y * WW + xb];
            s1a += va; s2a += va * va;
            s1b += vb; s2b += vb * vb;
        }
        double d1 = (double)s1a + (double)s1b;
        double d2 = (double)s2a + (double)s2b;
        for (int off = 32; off; off >>= 1) {
            d1 += __shfl_down(d1, off);
            d2 += __shfl_down(d2, off);
        }
        __shared__ double r1[4], r2[4];
        int lane = t & 63, wv = t >> 6;
        if (lane == 0) { r1[wv] = d1; r2[wv] = d2; }
        __syncthreads();
        if (t == 0) {
            atomicAdd(&sum1[32], r1[0] + r1[1] + r1[2] + r1[3]);
            atomicAdd(&sum2[32], r2[0] + r2[1] + r2[2] + r2[3]);
        }
    }
}

// ---------------- Kernel W1b: edges + sliding windows + frame totals --------
__global__ __launch_bounds__(512) void colsum_combine(
    const float* __restrict__ fr, const float* __restrict__ I1,
    const float* __restrict__ I2, float* __restrict__ cs1,
    float* __restrict__ cs2, double* __restrict__ sum1)
{
    int b = blockIdx.x;
    int x = threadIdx.x;
    const float* img = fr + (size_t)b * NPIX;
    float top[20], bot[20];
#pragma unroll
    for (int y = 0; y < 20; ++y) top[y] = img[(size_t)y * WW + x];
#pragma unroll
    for (int y = 0; y < 20; ++y) bot[y] = img[(size_t)(492 + y) * WW + x];

    float t1 = 0.f, t2 = 0.f, b1 = 0.f, b2 = 0.f;
#pragma unroll
    for (int y = 0; y < 20; ++y) {
        t1 += top[y]; t2 += top[y] * top[y];
        b1 += bot[y]; b2 += bot[y] * bot[y];
    }
    float i1 = I1[b * WW + x], i2 = I2[b * WW + x];

    double tot = (double)i1 + (double)t1 + (double)b1;
    for (int off = 32; off; off >>= 1) tot += __shfl_down(tot, off);
    __shared__ double red[8];
    int lane = x & 63, wv = x >> 6;
    if (lane == 0) red[wv] = tot;
    __syncthreads();
    if (x == 0) {
        double s = 0.0;
        for (int i = 0; i < 8; ++i) s += red[i];
        sum1[b] = s;
    }

    float s1 = i1 + t1, s2 = i2 + t2;
    size_t base = (size_t)b * NS * WW + x;
    cs1[base] = s1; cs2[base] = s2;
#pragma unroll
    for (int u = 1; u < NS; ++u) {
        float a = top[u-1], c = bot[u-1];
        s1 += c - a;
        s2 += c * c - a * a;
        cs1[base + (size_t)u * WW] = s1;
        cs2[base + (size_t)u * WW] = s2;
    }
}

// ---------------- Kernel W2: window sums -> denominator (wave per triple) ---
__global__ __launch_bounds__(256) void denom_kernel(
    const float* __restrict__ cs1, const float* __restrict__ cs2,
    const double* __restrict__ sum1, const double* __restrict__ sum2,
    float* __restrict__ denom)
{
    int wid  = blockIdx.x * 4 + (threadIdx.x >> 6);   // one wave per (b,u,v)
    int lane = threadIdx.x & 63;
    if (wid >= NB * NS * NS) return;
    int v  = wid % NS;
    int bu = wid / NS;
    const float* r1 = cs1 + (size_t)bu * WW + v;
    const float* r2 = cs2 + (size_t)bu * WW + v;
    double s1 = 0.0, s2 = 0.0;
    for (int x = lane; x < KWIN; x += 64) { s1 += (double)r1[x]; s2 += (double)r2[x]; }
    for (int off = 32; off; off >>= 1) {
        s1 += __shfl_down(s1, off);
        s2 += __shfl_down(s2, off);
    }
    if (lane == 0) {
        const double inv = 1.0 / ((double)KWIN * (double)KWIN);
        double m1 = s1 * inv, m2 = s2 * inv;
        double var = m2 - (m1 * m1) * inv + 1e-8;   // reference's formula
        if (var < 0.0) var = 0.0;
        double tv = sum2[32] - sum1[32] * sum1[32] * (1.0 / (double)NPIX) + 1e-8;
        denom[wid] = (float)sqrt(tv * var);
    }
}

// ---------------- Prep: frames fp32 -> bf16 interleaved (LDS transpose)
//                  + 21 dv-shifted bf16 template copies -----------------------
__global__ __launch_bounds__(256) void prep_kernel(
    const float* __restrict__ fr, const float* __restrict__ tpl,
    unsigned short* __restrict__ frBi, unsigned short* __restrict__ tplv)
{
    int blk = blockIdx.x;
    if (blk < 512) {
        int kbase   = blk * 512;        // k range [kbase, kbase+512)
        int kc8base = blk * 64;
        __shared__ unsigned short tile[64][264];   // [kc8][n*8+j], row pad 8 shorts
        int half = threadIdx.x >> 7;    // 0,1
        int tq   = threadIdx.x & 127;   // float4 index within a frame row
        int kc8l = tq >> 1;
        int j4   = (tq & 1) * 4;
#pragma unroll
        for (int n2 = 0; n2 < 32; n2 += 2) {
            int n = n2 + half;
            const float* src = fr + (size_t)n * NPIX + kbase + tq * 4;
            float4 v = *(const float4*)src;
            unsigned short* d = &tile[kc8l][n * 8 + j4];
            d[0] = f2bf(v.x); d[1] = f2bf(v.y); d[2] = f2bf(v.z); d[3] = f2bf(v.w);
        }
        __syncthreads();
        for (int c = threadIdx.x; c < 2048; c += 256) {
            int kl = c >> 5;
            int n  = c & 31;
            ushort8 o = *(ushort8*)&tile[kl][n * 8];
            *(ushort8*)(frBi + ((size_t)(kc8base + kl) * 32 + n) * 8) = o;
        }
    } else {
        int blk2 = blk - 512;           // 0..713
        int dv   = blk2 / 34;
        int prg  = blk2 % 34;
        int prEnd = min(16 * prg + 16, 532);
        for (int pr = 16 * prg; pr < prEnd; ++pr) {
            int sy = (pr + 502) & 511;  // (pr-10) mod 512
            const float* srow = tpl + (size_t)sy * WW;
            unsigned short* drow = tplv + ((size_t)dv * 532 + pr) * 512;
            for (int x = threadIdx.x; x < 512; x += 256) {
                int sx = (x - dv + 522) & 511;   // (x - dv + 10) mod 512
                drow[x] = f2bf(srow[sx]);
            }
        }
    }
}

// ---------------- Kernel C: implicit-GEMM correlation via MFMA --------------
// Block = 896 thr = 14 waves = all 28 m-tiles sharing ONE k-chunk (512 k).
// kb XCD-swizzled so 64 consecutive k-chunks land on one XCD -> overlapping
// A-slices stay L2-resident. NO atomics: dense float4 partial stores to
// part[kb][mtile][n][mr]; reduce_cc sums over kb.
__global__ __launch_bounds__(896) void corr_mfma(
    const unsigned short* __restrict__ frBi,
    const unsigned short* __restrict__ tplv,
    float* __restrict__ part)
{
    const int l   = threadIdx.x & 63;
    const int mg2 = threadIdx.x >> 6;      // wave 0..13 = m-pair group
    const int kb  = ((blockIdx.x & 7) << 6) | (blockIdx.x >> 3);  // XCD swizzle
    const int k0  = kb << 9;               // k-chunk base (512 each)
    const int kg  = l >> 4;                // k-group 0..3
    const int ln  = l & 15;

    const unsigned short* pA[2];
#pragma unroll
    for (int mt = 0; mt < 2; ++mt) {
        int m_g = 32 * mg2 + 16 * mt + ln;
        int du  = (m_g * 1561) >> 15;      // m_g/21 exact for m_g<=447
        int dv  = m_g - 21 * du;
        if (m_g >= 441) { du = 0; dv = 0; }   // pad rows: loaded, never used
        pA[mt] = tplv + ((size_t)(dv * 532 + 20 - du) * 512 + 8 * kg + k0);
    }
    const unsigned short* pB0 = frBi + ((size_t)k0 * 32 + kg * 256 + ln * 8);
    const unsigned short* pB1 = pB0 + 128;   // frames 16..31

    floatx4 acc00 = {}, acc01 = {}, acc10 = {}, acc11 = {};

#pragma unroll
    for (int ks = 0; ks < 16; ++ks) {      // 16 steps x 32 k = 512
        short8 A0 = *(const short8*)pA[0];
        short8 A1 = *(const short8*)pA[1];
        short8 B0 = *(const short8*)pB0;
        short8 B1 = *(const short8*)pB1;
        acc00 = __builtin_amdgcn_mfma_f32_16x16x32_bf16(A0, B0, acc00, 0, 0, 0);
        acc01 = __builtin_amdgcn_mfma_f32_16x16x32_bf16(A0, B1, acc01, 0, 0, 0);
        acc10 = __builtin_amdgcn_mfma_f32_16x16x32_bf16(A1, B0, acc10, 0, 0, 0);
        acc11 = __builtin_amdgcn_mfma_f32_16x16x32_bf16(A1, B1, acc11, 0, 0, 0);
        pA[0] += 32; pA[1] += 32; pB0 += 1024; pB1 += 1024;
    }

    // dense partial stores: part[((kb*28 + mtile)*32 + n)*16 + mr], mr=4kg+r
    {
        size_t base = ((size_t)kb * MT28 + 2 * mg2) * 32;
        floatx4* p;
        p = (floatx4*)(part + (base + ln)        * 16 + 4 * kg); *p = acc00;
        p = (floatx4*)(part + (base + 16 + ln)   * 16 + 4 * kg); *p = acc01;
        p = (floatx4*)(part + (base + 32 + ln)   * 16 + 4 * kg); *p = acc10;  // mtile+1, n=ln
        p = (floatx4*)(part + (base + 48 + ln)   * 16 + 4 * kg); *p = acc11;  // mtile+1, n=16+ln
    }
}

// ---------------- reduce partials over kb -> cc[n*441+m] --------------------
__global__ __launch_bounds__(256) void reduce_cc(
    const float* __restrict__ part, float* __restrict__ cc)
{
    int j = blockIdx.x * 256 + threadIdx.x;    // 0..14335 = (mtile*32+n)*16+mr
    float s = 0.f;
#pragma unroll 8
    for (int kb = 0; kb < NKB; ++kb)
        s += part[(size_t)kb * (MT28 * 32 * 16) + j];
    int mr    = j & 15;
    int n     = (j >> 4) & 31;
    int mtile = j >> 9;
    int m = mtile * 16 + mr;
    if (m < 441)
        cc[(size_t)n * 441 + m] = s;
}

// ---------------- Kernel S: argmax + log-parabola subpixel ------------------
__global__ __launch_bounds__(64) void argmax_kernel(
    const float* __restrict__ cc, const float* __restrict__ denom,
    const double* __restrict__ sum1, float* __restrict__ shifts)
{
    int b = blockIdx.x;
    const float* C = cc    + (size_t)b * NS * NS;
    const float* D = denom + (size_t)b * NS * NS;
    float corr = (float)(sum1[b] * sum1[32] * (1.0 / (double)NPIX));
    int l = threadIdx.x;
    float best = -1e30f; int bidx = NS * NS;
    for (int i = l; i < NS * NS; i += 64) {
        float v = fabsf(C[i] - corr) / D[i];
        if (v != v) v = 0.f;               // NaN -> 0 (matches reference)
        if (v > best) { best = v; bidx = i; }
    }
    for (int off = 32; off; off >>= 1) {
        float ov = __shfl_down(best, off);
        int   oi = __shfl_down(bidx, off);
        if (ov > best || (ov == best && oi < bidx)) { best = ov; bidx = oi; }
    }
    if (l == 0) {
        int shx = bidx / NS, shy = bidx % NS;
        auto nccAt = [&](int i, int j) -> float {
            i = (i < 0) ? i + NS : i; i = (i > NS - 1) ? NS - 1 : i;  // jnp wrap-then-clamp
            j = (j < 0) ? j + NS : j; j = (j > NS - 1) ? NS - 1 : j;
            float v = fabsf(C[i * NS + j] - corr) / D[i * NS + j];
            if (v != v) v = 0.f;
            return v;
        };
        float lc  = logf(nccAt(shx, shy));
        float lxm = logf(nccAt(shx - 1, shy));
        float lxp = logf(nccAt(shx + 1, shy));
        float lym = logf(nccAt(shx, shy - 1));
        float lyp = logf(nccAt(shx, shy + 1));
        float shxn = -(float)(shx - 10) - (lxm - lxp) / (2.f * lxm - 4.f * lc + 2.f * lxp);
        float shyn = -(float)(shy - 10) - (lym - lyp) / (2.f * lym - 4.f * lc + 2.f * lyp);
        shifts[b]      = shxn;   // dy
        shifts[32 + b] = shyn;   // dx
    }
}

// ---------------- Kernel B: bilinear warp + transposed write ----------------
__device__ __forceinline__ float samp(const float* __restrict__ img, int y, int x) {
    bool valid = (y >= 0) & (y < HH) & (x >= 0) & (x < WW);
    int yc = min(max(y, 0), HH - 1), xc = min(max(x, 0), WW - 1);
    float v = img[(size_t)yc * WW + xc];
    return valid ? v : 0.f;
}

__global__ __launch_bounds__(256) void warp_kernel(
    const float* __restrict__ fr, const float* __restrict__ shifts,
    float* __restrict__ out)
{
    int b  = blockIdx.z;
    int h0 = blockIdx.y * 32;
    int w0 = blockIdx.x * 32;
    float dy = shifts[b], dx = shifts[32 + b];
    const float* img = fr + (size_t)b * NPIX;
    __shared__ float tile[32][33];
    int tx = threadIdx.x & 31;
    int tz = threadIdx.x >> 5;
#pragma unroll
    for (int s = 0; s < 4; ++s) {
        int h = h0 + tz + 8 * s;
        int w = w0 + tx;
        float yq = (float)h - dy;
        float xq = (float)w - dx;
        float y0f = floorf(yq), x0f = floorf(xq);
        float wy = yq - y0f, wx = xq - x0f;
        int y0 = (int)y0f, x0 = (int)x0f;
        float v00 = samp(img, y0,     x0);
        float v01 = samp(img, y0,     x0 + 1);
        float v10 = samp(img, y0 + 1, x0);
        float v11 = samp(img, y0 + 1, x0 + 1);
        float val = v00 * (1.f - wy) * (1.f - wx) + v01 * (1.f - wy) * wx
                  + v10 * wy * (1.f - wx)         + v11 * wy * wx;
        tile[tz + 8 * s][tx] = val;
    }
    __syncthreads();
#pragma unroll
    for (int s = 0; s < 4; ++s) {
        int hh = tx;
        int ww = tz + 8 * s;
        out[(size_t)b * NPIX + (size_t)(w0 + ww) * HH + (h0 + hh)] = tile[hh][ww];
    }
}

// ---------------- launch ----------------------------------------------------
extern "C" void kernel_launch(void* const* d_in, const int* in_sizes, int n_in,
                              void* d_out, int out_size, void* d_ws, size_t ws_size,
                              hipStream_t stream) {
    const float* fr  = (const float*)d_in[0];   // (1,32,512,512,1) flat
    const float* tpl = (const float*)d_in[1];   // (512,512)
    float* out = (float*)d_out;
    char* ws = (char*)d_ws;

    // ws layout (~58 MB). frBi OVERLAYS cs1/cs2 (consumed by denom first).
    double* sum1    = (double*)(ws + 0);          // 33 doubles
    double* sum2    = (double*)(ws + 512);        // 33 doubles
    float*  cc      = (float*) (ws + 4096);       // 32*441 floats
    float*  I1      = (float*) (ws + 61440);      // 32*512 floats
    float*  I2      = (float*) (ws + 126976);     // 32*512 floats
    float*  shifts  = (float*) (ws + 196608);     // 64 floats
    float*  denom   = (float*) (ws + 200704);     // 32*441 floats
    float*  cs1     = (float*) (ws + 262144);     // 32*21*512 floats
    float*  cs2     = (float*) (ws + 1638400);    // 32*21*512 floats
    unsigned short* frBi = (unsigned short*)(ws + 262144);    // 16.78 MB (after denom)
    unsigned short* tplv = (unsigned short*)(ws + 17039360);  // 11.44 MB
    float*  part    = (float*) (ws + 28508160);   // 512*28*32*16 floats = 29.36 MB

    hipMemsetAsync(ws, 0, 192512, stream);       // zero sums + cc + I1/I2

    colsum_phase1 <<<264, 256, 0, stream>>>(fr, tpl, I1, I2, sum1, sum2);
    colsum_combine<<<32, 512, 0, stream>>>(fr, I1, I2, cs1, cs2, sum1);
    denom_kernel  <<<(NB * NS * NS + 3) / 4, 256, 0, stream>>>(cs1, cs2, sum1, sum2, denom);
    // prep AFTER denom (frBi overlays cs1/cs2)
    prep_kernel   <<<1226, 256, 0, stream>>>(fr, tpl, frBi, tplv);
    corr_mfma     <<<512, 896, 0, stream>>>(frBi, tplv, part);
    reduce_cc     <<<56, 256, 0, stream>>>(part, cc);
    argmax_kernel <<<32, 64, 0, stream>>>(cc, denom, sum1, shifts);
    warp_kernel   <<<dim3(16, 16, 32), 256, 0, stream>>>(fr, shifts, out);
}

// Round 11
// 170.318 us; speedup vs baseline: 2.5903x; 1.1820x over previous
//
#include <hip/hip_runtime.h>
#include <math.h>

#define HH 512
#define WW 512
#define NPIX (HH*WW)
#define NB 32
#define NS 21           // 2*MS+1 shifts per axis
#define KWIN 492        // window size (H - 2*10)
#define NKB 512         // split-K chunks
#define MT28 28         // m-tiles (448 = 28*16, M=441 padded)
#define PARTSZ (MT28*32*16)

typedef __attribute__((ext_vector_type(8))) short short8;
typedef __attribute__((ext_vector_type(8))) unsigned short ushort8;
typedef __attribute__((ext_vector_type(4))) float floatx4;

__device__ __forceinline__ unsigned short f2bf(float f) {
    unsigned u = __float_as_uint(f);
    unsigned r = (u + 0x7fffu + ((u >> 16) & 1u)) >> 16;
    return (unsigned short)r;
}

// ---------------- Stage 1 (fused): conv frames -> bf16 interleave,
//   interior column sums, template sums, 21 dv-shifted bf16 template copies.
// blocks [0,512):     conv frames, k-chunk = blk (LDS transpose, 2 frame-halves)
// blocks [512,1024):  interior colsums: (b, ygroup of ~30 rows) -> I1/I2 atomics
// blocks [1024,1032): template sums -> sum1[32], sum2[32]
// blocks [1032,1746): tplv build
__global__ __launch_bounds__(256) void stage1(
    const float* __restrict__ fr, const float* __restrict__ tpl,
    unsigned short* __restrict__ frBi, unsigned short* __restrict__ tplv,
    float* __restrict__ I1, float* __restrict__ I2,
    double* __restrict__ sum1, double* __restrict__ sum2)
{
    __shared__ unsigned short tile[64][136];   // 17 KB (conv branch only)
    int blk = blockIdx.x;
    int t   = threadIdx.x;
    if (blk < 512) {
        int kbase   = blk * 512;        // k range [kbase, kbase+512)
        int kc8base = blk * 64;
        int sub  = t >> 7;              // 0,1
        int tq   = t & 127;             // float4 index within a frame row
        int kc8l = tq >> 1;
        int j4   = (tq & 1) * 4;
#pragma unroll
        for (int h = 0; h < 2; ++h) {   // frame halves 0..15, 16..31
#pragma unroll
            for (int n2 = 0; n2 < 16; n2 += 2) {
                int nl = n2 + sub;
                const float* src = fr + (size_t)(h * 16 + nl) * NPIX + kbase + tq * 4;
                float4 v = *(const float4*)src;
                unsigned short* d = &tile[kc8l][nl * 8 + j4];
                d[0] = f2bf(v.x); d[1] = f2bf(v.y); d[2] = f2bf(v.z); d[3] = f2bf(v.w);
            }
            __syncthreads();
            for (int c = t; c < 1024; c += 256) {
                int kl = c >> 4;
                int nl = c & 15;
                ushort8 o = *(ushort8*)&tile[kl][nl * 8];
                *(ushort8*)(frBi + ((size_t)(kc8base + kl) * 32 + h * 16 + nl) * 8) = o;
            }
            __syncthreads();           // WAR before next half
        }
    } else if (blk < 1024) {
        int id = blk - 512;
        int b  = id >> 4;
        int yg = id & 15;
        int y0, ny;
        if (yg < 8) { y0 = 20 + 30 * yg; ny = 30; }
        else        { y0 = 260 + 29 * (yg - 8); ny = 29; }
        const float* img = fr + (size_t)b * NPIX;
        int xa = t, xb = t + 256;
        float s1a = 0.f, s2a = 0.f, s1b = 0.f, s2b = 0.f;
        for (int y = y0; y < y0 + ny; ++y) {
            float va = img[(size_t)y * WW + xa];
            float vb = img[(size_t)y * WW + xb];
            s1a += va; s2a += va * va;
            s1b += vb; s2b += vb * vb;
        }
        atomicAdd(&I1[b * WW + xa], s1a); atomicAdd(&I2[b * WW + xa], s2a);
        atomicAdd(&I1[b * WW + xb], s1b); atomicAdd(&I2[b * WW + xb], s2b);
    } else if (blk < 1032) {
        int gq = blk - 1024;           // rows [64gq, 64gq+64)
        int y0 = 64 * gq;
        int xa = t, xb = t + 256;
        float s1a = 0.f, s2a = 0.f, s1b = 0.f, s2b = 0.f;
        for (int y = y0; y < y0 + 64; ++y) {
            float va = tpl[(size_t)y * WW + xa];
            float vb = tpl[(size_t)y * WW + xb];
            s1a += va; s2a += va * va;
            s1b += vb; s2b += vb * vb;
        }
        double d1 = (double)s1a + (double)s1b;
        double d2 = (double)s2a + (double)s2b;
        for (int off = 32; off; off >>= 1) {
            d1 += __shfl_down(d1, off);
            d2 += __shfl_down(d2, off);
        }
        __shared__ double r1[4], r2[4];
        int lane = t & 63, wv = t >> 6;
        if (lane == 0) { r1[wv] = d1; r2[wv] = d2; }
        __syncthreads();
        if (t == 0) {
            atomicAdd(&sum1[32], r1[0] + r1[1] + r1[2] + r1[3]);
            atomicAdd(&sum2[32], r2[0] + r2[1] + r2[2] + r2[3]);
        }
    } else {
        int blk2 = blk - 1032;          // 0..713
        int dv   = blk2 / 34;
        int prg  = blk2 % 34;
        int prEnd = min(16 * prg + 16, 532);
        for (int pr = 16 * prg; pr < prEnd; ++pr) {
            int sy = (pr + 502) & 511;  // (pr-10) mod 512
            const float* srow = tpl + (size_t)sy * WW;
            unsigned short* drow = tplv + ((size_t)dv * 532 + pr) * 512;
            for (int x = t; x < 512; x += 256) {
                int sx = (x - dv + 522) & 511;   // (x - dv + 10) mod 512
                drow[x] = f2bf(srow[sx]);
            }
        }
    }
}

// ---------------- Stage 2 (fused): edges + frame totals + DENOMINATOR -------
// Block = frame b (512 threads = columns). Window sum over x in [v, v+492)
// = total - left-edge(v) - right-edge(v): only 40 edge columns + row total.
__global__ __launch_bounds__(512) void stage2(
    const float* __restrict__ fr, const float* __restrict__ I1,
    const float* __restrict__ I2, double* __restrict__ sum1,
    const double* __restrict__ sum2, float* __restrict__ denom)
{
    int b = blockIdx.x;
    int x = threadIdx.x;
    const float* img = fr + (size_t)b * NPIX;
    float top[20], bot[20];
#pragma unroll
    for (int y = 0; y < 20; ++y) top[y] = img[(size_t)y * WW + x];
#pragma unroll
    for (int y = 0; y < 20; ++y) bot[y] = img[(size_t)(492 + y) * WW + x];

    float t1 = 0.f, t2 = 0.f, b1 = 0.f, b2 = 0.f;
#pragma unroll
    for (int y = 0; y < 20; ++y) {
        t1 += top[y]; t2 += top[y] * top[y];
        b1 += bot[y]; b2 += bot[y] * bot[y];
    }
    float i1 = I1[b * WW + x], i2 = I2[b * WW + x];

    __shared__ double wr1[NS][8], wr2[NS][8], wrT[8];
    __shared__ float  e1[NS][40], e2[NS][40];
    __shared__ double totals1[NS], totals2[NS];
    int lane = x & 63, wv = x >> 6;

    // frame total -> sum1[b]
    double tot = (double)i1 + (double)t1 + (double)b1;
    for (int off = 32; off; off >>= 1) tot += __shfl_down(tot, off);
    if (lane == 0) wrT[wv] = tot;

    // per-u column-window sums (register sliding), block totals + edge columns
    float s1 = i1 + t1, s2 = i2 + t2;
#pragma unroll
    for (int u = 0; u < NS; ++u) {
        if (u) {
            float a = top[u-1], c = bot[u-1];
            s1 += c - a;
            s2 += c * c - a * a;
        }
        double d1 = (double)s1, d2 = (double)s2;
        for (int off = 32; off; off >>= 1) {
            d1 += __shfl_down(d1, off);
            d2 += __shfl_down(d2, off);
        }
        if (lane == 0) { wr1[u][wv] = d1; wr2[u][wv] = d2; }
        if (x < 20)        { e1[u][x]       = s1; e2[u][x]       = s2; }
        else if (x >= 492) { e1[u][x - 472] = s1; e2[u][x - 472] = s2; }
    }
    __syncthreads();
    if (x == 0) {
        double s = 0.0;
        for (int i = 0; i < 8; ++i) s += wrT[i];
        sum1[b] = s;
    }
    if (x < NS) {
        double a = 0.0, c = 0.0;
        for (int i = 0; i < 8; ++i) { a += wr1[x][i]; c += wr2[x][i]; }
        totals1[x] = a; totals2[x] = c;
    }
    __syncthreads();
    if (x < NS * NS) {
        int u = x / NS, v = x - NS * u;
        double S1 = totals1[u], S2 = totals2[u];
        for (int j = 0; j < v; ++j)  { S1 -= (double)e1[u][j];      S2 -= (double)e2[u][j]; }
        for (int j = v; j < 20; ++j) { S1 -= (double)e1[u][20 + j]; S2 -= (double)e2[u][20 + j]; }
        const double inv = 1.0 / ((double)KWIN * (double)KWIN);
        double m1 = S1 * inv, m2 = S2 * inv;
        double var = m2 - (m1 * m1) * inv + 1e-8;   // reference's formula
        if (var < 0.0) var = 0.0;
        double tv = sum2[32] - sum1[32] * sum1[32] * (1.0 / (double)NPIX) + 1e-8;
        denom[(size_t)b * NS * NS + x] = (float)sqrt(tv * var);
    }
}

// ---------------- Kernel C: implicit-GEMM correlation via MFMA --------------
// (unchanged from round 10: 14 waves share one k-chunk, XCD-swizzled kb,
//  dense partial stores, no atomics)
__global__ __launch_bounds__(896) void corr_mfma(
    const unsigned short* __restrict__ frBi,
    const unsigned short* __restrict__ tplv,
    float* __restrict__ part)
{
    const int l   = threadIdx.x & 63;
    const int mg2 = threadIdx.x >> 6;      // wave 0..13 = m-pair group
    const int kb  = ((blockIdx.x & 7) << 6) | (blockIdx.x >> 3);  // XCD swizzle
    const int k0  = kb << 9;               // k-chunk base (512 each)
    const int kg  = l >> 4;                // k-group 0..3
    const int ln  = l & 15;

    const unsigned short* pA[2];
#pragma unroll
    for (int mt = 0; mt < 2; ++mt) {
        int m_g = 32 * mg2 + 16 * mt + ln;
        int du  = (m_g * 1561) >> 15;      // m_g/21 exact for m_g<=447
        int dv  = m_g - 21 * du;
        if (m_g >= 441) { du = 0; dv = 0; }   // pad rows: loaded, never used
        pA[mt] = tplv + ((size_t)(dv * 532 + 20 - du) * 512 + 8 * kg + k0);
    }
    const unsigned short* pB0 = frBi + ((size_t)k0 * 32 + kg * 256 + ln * 8);
    const unsigned short* pB1 = pB0 + 128;   // frames 16..31

    floatx4 acc00 = {}, acc01 = {}, acc10 = {}, acc11 = {};

#pragma unroll
    for (int ks = 0; ks < 16; ++ks) {      // 16 steps x 32 k = 512
        short8 A0 = *(const short8*)pA[0];
        short8 A1 = *(const short8*)pA[1];
        short8 B0 = *(const short8*)pB0;
        short8 B1 = *(const short8*)pB1;
        acc00 = __builtin_amdgcn_mfma_f32_16x16x32_bf16(A0, B0, acc00, 0, 0, 0);
        acc01 = __builtin_amdgcn_mfma_f32_16x16x32_bf16(A0, B1, acc01, 0, 0, 0);
        acc10 = __builtin_amdgcn_mfma_f32_16x16x32_bf16(A1, B0, acc10, 0, 0, 0);
        acc11 = __builtin_amdgcn_mfma_f32_16x16x32_bf16(A1, B1, acc11, 0, 0, 0);
        pA[0] += 32; pA[1] += 32; pB0 += 1024; pB1 += 1024;
    }

    // dense partial stores: part[((kb*28 + mtile)*32 + n)*16 + mr], mr=4kg+r
    {
        size_t base = ((size_t)kb * MT28 + 2 * mg2) * 32;
        floatx4* p;
        p = (floatx4*)(part + (base + ln)      * 16 + 4 * kg); *p = acc00;
        p = (floatx4*)(part + (base + 16 + ln) * 16 + 4 * kg); *p = acc01;
        p = (floatx4*)(part + (base + 32 + ln) * 16 + 4 * kg); *p = acc10;
        p = (floatx4*)(part + (base + 48 + ln) * 16 + 4 * kg); *p = acc11;
    }
}

// ---------------- reduce partials over kb -> cc[n*441+m] --------------------
// 448 blocks: 8 kb-octants x 56 j-groups; 8 spread atomics per cc element.
__global__ __launch_bounds__(256) void reduce_cc(
    const float* __restrict__ part, float* __restrict__ cc)
{
    int oct = blockIdx.x / 56;                       // 0..7
    int j   = (blockIdx.x % 56) * 256 + threadIdx.x; // 0..14335
    const float* p = part + (size_t)(oct * 64) * PARTSZ + j;
    float s = 0.f;
#pragma unroll 8
    for (int i = 0; i < 64; ++i)
        s += p[(size_t)i * PARTSZ];
    int mr    = j & 15;
    int n     = (j >> 4) & 31;
    int mtile = j >> 9;
    int m = mtile * 16 + mr;
    if (m < 441)
        atomicAdd(&cc[(size_t)n * 441 + m], s);
}

// ---------------- Kernel S: argmax + log-parabola subpixel ------------------
__global__ __launch_bounds__(64) void argmax_kernel(
    const float* __restrict__ cc, const float* __restrict__ denom,
    const double* __restrict__ sum1, float* __restrict__ shifts)
{
    int b = blockIdx.x;
    const float* C = cc    + (size_t)b * NS * NS;
    const float* D = denom + (size_t)b * NS * NS;
    float corr = (float)(sum1[b] * sum1[32] * (1.0 / (double)NPIX));
    int l = threadIdx.x;
    float best = -1e30f; int bidx = NS * NS;
    for (int i = l; i < NS * NS; i += 64) {
        float v = fabsf(C[i] - corr) / D[i];
        if (v != v) v = 0.f;               // NaN -> 0 (matches reference)
        if (v > best) { best = v; bidx = i; }
    }
    for (int off = 32; off; off >>= 1) {
        float ov = __shfl_down(best, off);
        int   oi = __shfl_down(bidx, off);
        if (ov > best || (ov == best && oi < bidx)) { best = ov; bidx = oi; }
    }
    if (l == 0) {
        int shx = bidx / NS, shy = bidx % NS;
        auto nccAt = [&](int i, int j) -> float {
            i = (i < 0) ? i + NS : i; i = (i > NS - 1) ? NS - 1 : i;  // jnp wrap-then-clamp
            j = (j < 0) ? j + NS : j; j = (j > NS - 1) ? NS - 1 : j;
            float v = fabsf(C[i * NS + j] - corr) / D[i * NS + j];
            if (v != v) v = 0.f;
            return v;
        };
        float lc  = logf(nccAt(shx, shy));
        float lxm = logf(nccAt(shx - 1, shy));
        float lxp = logf(nccAt(shx + 1, shy));
        float lym = logf(nccAt(shx, shy - 1));
        float lyp = logf(nccAt(shx, shy + 1));
        float shxn = -(float)(shx - 10) - (lxm - lxp) / (2.f * lxm - 4.f * lc + 2.f * lxp);
        float shyn = -(float)(shy - 10) - (lym - lyp) / (2.f * lym - 4.f * lc + 2.f * lyp);
        shifts[b]      = shxn;   // dy
        shifts[32 + b] = shyn;   // dx
    }
}

// ---------------- Kernel B: bilinear warp + transposed write ----------------
__device__ __forceinline__ float samp(const float* __restrict__ img, int y, int x) {
    bool valid = (y >= 0) & (y < HH) & (x >= 0) & (x < WW);
    int yc = min(max(y, 0), HH - 1), xc = min(max(x, 0), WW - 1);
    float v = img[(size_t)yc * WW + xc];
    return valid ? v : 0.f;
}

__global__ __launch_bounds__(256) void warp_kernel(
    const float* __restrict__ fr, const float* __restrict__ shifts,
    float* __restrict__ out)
{
    int b  = blockIdx.z;
    int h0 = blockIdx.y * 32;
    int w0 = blockIdx.x * 32;
    float dy = shifts[b], dx = shifts[32 + b];
    const float* img = fr + (size_t)b * NPIX;
    __shared__ float tile[32][33];
    int tx = threadIdx.x & 31;
    int tz = threadIdx.x >> 5;
#pragma unroll
    for (int s = 0; s < 4; ++s) {
        int h = h0 + tz + 8 * s;
        int w = w0 + tx;
        float yq = (float)h - dy;
        float xq = (float)w - dx;
        float y0f = floorf(yq), x0f = floorf(xq);
        float wy = yq - y0f, wx = xq - x0f;
        int y0 = (int)y0f, x0 = (int)x0f;
        float v00 = samp(img, y0,     x0);
        float v01 = samp(img, y0,     x0 + 1);
        float v10 = samp(img, y0 + 1, x0);
        float v11 = samp(img, y0 + 1, x0 + 1);
        float val = v00 * (1.f - wy) * (1.f - wx) + v01 * (1.f - wy) * wx
                  + v10 * wy * (1.f - wx)         + v11 * wy * wx;
        tile[tz + 8 * s][tx] = val;
    }
    __syncthreads();
#pragma unroll
    for (int s = 0; s < 4; ++s) {
        int hh = tx;
        int ww = tz + 8 * s;
        out[(size_t)b * NPIX + (size_t)(w0 + ww) * HH + (h0 + hh)] = tile[hh][ww];
    }
}

// ---------------- launch ----------------------------------------------------
extern "C" void kernel_launch(void* const* d_in, const int* in_sizes, int n_in,
                              void* d_out, int out_size, void* d_ws, size_t ws_size,
                              hipStream_t stream) {
    const float* fr  = (const float*)d_in[0];   // (1,32,512,512,1) flat
    const float* tpl = (const float*)d_in[1];   // (512,512)
    float* out = (float*)d_out;
    char* ws = (char*)d_ws;

    // ws layout (~58 MB)
    double* sum1    = (double*)(ws + 0);          // 33 doubles
    double* sum2    = (double*)(ws + 512);        // 33 doubles
    float*  cc      = (float*) (ws + 4096);       // 32*441 floats (zeroed)
    float*  I1      = (float*) (ws + 61440);      // 32*512 floats (zeroed)
    float*  I2      = (float*) (ws + 126976);     // 32*512 floats (zeroed)
    float*  shifts  = (float*) (ws + 196608);     // 64 floats
    float*  denom   = (float*) (ws + 200704);     // 32*441 floats
    unsigned short* frBi = (unsigned short*)(ws + 262144);    // 16.78 MB
    unsigned short* tplv = (unsigned short*)(ws + 17039360);  // 11.44 MB
    float*  part    = (float*) (ws + 28508160);   // 512*28*32*16 floats = 29.36 MB

    hipMemsetAsync(ws, 0, 192512, stream);       // zero sums + cc + I1/I2

    stage1       <<<1746, 256, 0, stream>>>(fr, tpl, frBi, tplv, I1, I2, sum1, sum2);
    stage2       <<<32, 512, 0, stream>>>(fr, I1, I2, sum1, sum2, denom);
    corr_mfma    <<<512, 896, 0, stream>>>(frBi, tplv, part);
    reduce_cc    <<<448, 256, 0, stream>>>(part, cc);
    argmax_kernel<<<32, 64, 0, stream>>>(cc, denom, sum1, shifts);
    warp_kernel  <<<dim3(16, 16, 32), 256, 0, stream>>>(fr, shifts, out);
}

// Round 12
// 163.589 us; speedup vs baseline: 2.6968x; 1.0411x over previous
//
#include <hip/hip_runtime.h>
#include <math.h>

#define HH 512
#define WW 512
#define NPIX (HH*WW)
#define NB 32
#define NS 21           // 2*MS+1 shifts per axis
#define KWIN 492        // window size (H - 2*10)
#define NKB 256         // split-K chunks (1024 k each)
#define MT28 28         // m-tiles (448 = 28*16, M=441 padded)
#define PARTSZ (MT28*32*16)

typedef __attribute__((ext_vector_type(8))) short short8;
typedef __attribute__((ext_vector_type(8))) unsigned short ushort8;
typedef __attribute__((ext_vector_type(4))) float floatx4;

__device__ __forceinline__ unsigned short f2bf(float f) {
    unsigned u = __float_as_uint(f);
    unsigned r = (u + 0x7fffu + ((u >> 16) & 1u)) >> 16;
    return (unsigned short)r;
}

// ---------------- Stage 1 (fused): conv frames -> bf16 interleave,
//   interior column sums, template sums, 21 dv-shifted bf16 template copies.
__global__ __launch_bounds__(256) void stage1(
    const float* __restrict__ fr, const float* __restrict__ tpl,
    unsigned short* __restrict__ frBi, unsigned short* __restrict__ tplv,
    float* __restrict__ I1, float* __restrict__ I2,
    double* __restrict__ sum1, double* __restrict__ sum2)
{
    __shared__ unsigned short tile[64][136];   // 17 KB (conv branch only)
    int blk = blockIdx.x;
    int t   = threadIdx.x;
    if (blk < 512) {
        int kbase   = blk * 512;        // k range [kbase, kbase+512)
        int kc8base = blk * 64;
        int sub  = t >> 7;              // 0,1
        int tq   = t & 127;             // float4 index within a frame row
        int kc8l = tq >> 1;
        int j4   = (tq & 1) * 4;
#pragma unroll
        for (int h = 0; h < 2; ++h) {   // frame halves 0..15, 16..31
#pragma unroll
            for (int n2 = 0; n2 < 16; n2 += 2) {
                int nl = n2 + sub;
                const float* src = fr + (size_t)(h * 16 + nl) * NPIX + kbase + tq * 4;
                float4 v = *(const float4*)src;
                unsigned short* d = &tile[kc8l][nl * 8 + j4];
                d[0] = f2bf(v.x); d[1] = f2bf(v.y); d[2] = f2bf(v.z); d[3] = f2bf(v.w);
            }
            __syncthreads();
            for (int c = t; c < 1024; c += 256) {
                int kl = c >> 4;
                int nl = c & 15;
                ushort8 o = *(ushort8*)&tile[kl][nl * 8];
                *(ushort8*)(frBi + ((size_t)(kc8base + kl) * 32 + h * 16 + nl) * 8) = o;
            }
            __syncthreads();           // WAR before next half
        }
    } else if (blk < 1024) {
        int id = blk - 512;
        int b  = id >> 4;
        int yg = id & 15;
        int y0, ny;
        if (yg < 8) { y0 = 20 + 30 * yg; ny = 30; }
        else        { y0 = 260 + 29 * (yg - 8); ny = 29; }
        const float* img = fr + (size_t)b * NPIX;
        int xa = t, xb = t + 256;
        float s1a = 0.f, s2a = 0.f, s1b = 0.f, s2b = 0.f;
        for (int y = y0; y < y0 + ny; ++y) {
            float va = img[(size_t)y * WW + xa];
            float vb = img[(size_t)y * WW + xb];
            s1a += va; s2a += va * va;
            s1b += vb; s2b += vb * vb;
        }
        atomicAdd(&I1[b * WW + xa], s1a); atomicAdd(&I2[b * WW + xa], s2a);
        atomicAdd(&I1[b * WW + xb], s1b); atomicAdd(&I2[b * WW + xb], s2b);
    } else if (blk < 1032) {
        int gq = blk - 1024;           // rows [64gq, 64gq+64)
        int y0 = 64 * gq;
        int xa = t, xb = t + 256;
        float s1a = 0.f, s2a = 0.f, s1b = 0.f, s2b = 0.f;
        for (int y = y0; y < y0 + 64; ++y) {
            float va = tpl[(size_t)y * WW + xa];
            float vb = tpl[(size_t)y * WW + xb];
            s1a += va; s2a += va * va;
            s1b += vb; s2b += vb * vb;
        }
        double d1 = (double)s1a + (double)s1b;
        double d2 = (double)s2a + (double)s2b;
        for (int off = 32; off; off >>= 1) {
            d1 += __shfl_down(d1, off);
            d2 += __shfl_down(d2, off);
        }
        __shared__ double r1[4], r2[4];
        int lane = t & 63, wv = t >> 6;
        if (lane == 0) { r1[wv] = d1; r2[wv] = d2; }
        __syncthreads();
        if (t == 0) {
            atomicAdd(&sum1[32], r1[0] + r1[1] + r1[2] + r1[3]);
            atomicAdd(&sum2[32], r2[0] + r2[1] + r2[2] + r2[3]);
        }
    } else {
        int blk2 = blk - 1032;          // 0..713
        int dv   = blk2 / 34;
        int prg  = blk2 % 34;
        int prEnd = min(16 * prg + 16, 532);
        for (int pr = 16 * prg; pr < prEnd; ++pr) {
            int sy = (pr + 502) & 511;  // (pr-10) mod 512
            const float* srow = tpl + (size_t)sy * WW;
            unsigned short* drow = tplv + ((size_t)dv * 532 + pr) * 512;
            for (int x = t; x < 512; x += 256) {
                int sx = (x - dv + 522) & 511;   // (x - dv + 10) mod 512
                drow[x] = f2bf(srow[sx]);
            }
        }
    }
}

// ---------------- Kernel C: implicit-GEMM correlation via MFMA --------------
// NKB=256 chunks of 1024 k. Block = 448 thr = 7 waves = HALF the m-tiles;
// grid 512 = 2 blocks/CU (28 waves/CU). kb XCD-swizzled (32 consecutive
// chunks per XCD). Dense partial stores, no atomics.
__global__ __launch_bounds__(448) void corr_mfma(
    const unsigned short* __restrict__ frBi,
    const unsigned short* __restrict__ tplv,
    float* __restrict__ part)
{
    const int l    = threadIdx.x & 63;
    const int mg2  = threadIdx.x >> 6;     // wave 0..6
    const int half = blockIdx.x & 1;
    const int idx  = blockIdx.x >> 1;      // 0..255
    const int kb   = ((idx & 7) << 5) | (idx >> 3);   // XCD swizzle
    const int k0   = kb << 10;             // k-chunk base (1024 each)
    const int kg   = l >> 4;               // k-group 0..3
    const int ln   = l & 15;
    const int tp   = 7 * half + mg2;       // tile-pair 0..13

    const unsigned short* pA[2];
#pragma unroll
    for (int mt = 0; mt < 2; ++mt) {
        int m_g = 32 * tp + 16 * mt + ln;
        int du  = (m_g * 1561) >> 15;      // m_g/21 exact for m_g<=447
        int dv  = m_g - 21 * du;
        if (m_g >= 441) { du = 0; dv = 0; }   // pad rows: loaded, never used
        pA[mt] = tplv + ((size_t)(dv * 532 + 20 - du) * 512 + 8 * kg + k0);
    }
    const unsigned short* pB0 = frBi + ((size_t)k0 * 32 + kg * 256 + ln * 8);
    const unsigned short* pB1 = pB0 + 128;   // frames 16..31

    floatx4 acc00 = {}, acc01 = {}, acc10 = {}, acc11 = {};

#pragma unroll
    for (int ks = 0; ks < 32; ++ks) {      // 32 steps x 32 k = 1024
        short8 A0 = *(const short8*)pA[0];
        short8 A1 = *(const short8*)pA[1];
        short8 B0 = *(const short8*)pB0;
        short8 B1 = *(const short8*)pB1;
        acc00 = __builtin_amdgcn_mfma_f32_16x16x32_bf16(A0, B0, acc00, 0, 0, 0);
        acc01 = __builtin_amdgcn_mfma_f32_16x16x32_bf16(A0, B1, acc01, 0, 0, 0);
        acc10 = __builtin_amdgcn_mfma_f32_16x16x32_bf16(A1, B0, acc10, 0, 0, 0);
        acc11 = __builtin_amdgcn_mfma_f32_16x16x32_bf16(A1, B1, acc11, 0, 0, 0);
        pA[0] += 32; pA[1] += 32; pB0 += 1024; pB1 += 1024;
    }

    // dense partial stores: part[((kb*28 + mtile)*32 + n)*16 + mr], mr=4kg+r
    {
        size_t base = ((size_t)kb * MT28 + 2 * tp) * 32;
        floatx4* p;
        p = (floatx4*)(part + (base + ln)      * 16 + 4 * kg); *p = acc00;
        p = (floatx4*)(part + (base + 16 + ln) * 16 + 4 * kg); *p = acc01;
        p = (floatx4*)(part + (base + 32 + ln) * 16 + 4 * kg); *p = acc10;
        p = (floatx4*)(part + (base + 48 + ln) * 16 + 4 * kg); *p = acc11;
    }
}

// ---------------- reduce partials + (fused) stage2 denominator --------------
// blocks [0,224):  reduce: oct = blk/28 (32 kb each), j = (blk%28)*512 + t
// blocks [224,256): stage2 for frame b = blk-224 (edges + totals + denom)
__global__ __launch_bounds__(512) void reduce_stage2(
    const float* __restrict__ part, float* __restrict__ cc,
    const float* __restrict__ fr, const float* __restrict__ I1,
    const float* __restrict__ I2, double* __restrict__ sum1,
    const double* __restrict__ sum2, float* __restrict__ denom)
{
    __shared__ double wr1[NS][8], wr2[NS][8], wrT[8];
    __shared__ float  e1[NS][40], e2[NS][40];
    __shared__ double totals1[NS], totals2[NS];

    int blk = blockIdx.x;
    if (blk < 224) {
        int oct = blk / 28;                        // 0..7 (32 kb each)
        int j   = (blk % 28) * 512 + threadIdx.x;  // 0..14335
        const float* p = part + (size_t)(oct * 32) * PARTSZ + j;
        float s = 0.f;
#pragma unroll 8
        for (int i = 0; i < 32; ++i)
            s += p[(size_t)i * PARTSZ];
        int mr    = j & 15;
        int n     = (j >> 4) & 31;
        int mtile = j >> 9;
        int m = mtile * 16 + mr;
        if (m < 441)
            atomicAdd(&cc[(size_t)n * 441 + m], s);
        return;
    }

    int b = blk - 224;
    int x = threadIdx.x;
    const float* img = fr + (size_t)b * NPIX;
    float top[20], bot[20];
#pragma unroll
    for (int y = 0; y < 20; ++y) top[y] = img[(size_t)y * WW + x];
#pragma unroll
    for (int y = 0; y < 20; ++y) bot[y] = img[(size_t)(492 + y) * WW + x];

    float t1 = 0.f, t2 = 0.f, b1 = 0.f, b2 = 0.f;
#pragma unroll
    for (int y = 0; y < 20; ++y) {
        t1 += top[y]; t2 += top[y] * top[y];
        b1 += bot[y]; b2 += bot[y] * bot[y];
    }
    float i1 = I1[b * WW + x], i2 = I2[b * WW + x];
    int lane = x & 63, wv = x >> 6;

    // frame total -> sum1[b]
    double tot = (double)i1 + (double)t1 + (double)b1;
    for (int off = 32; off; off >>= 1) tot += __shfl_down(tot, off);
    if (lane == 0) wrT[wv] = tot;

    // per-u column-window sums (register sliding), block totals + edge columns
    float s1 = i1 + t1, s2 = i2 + t2;
#pragma unroll
    for (int u = 0; u < NS; ++u) {
        if (u) {
            float a = top[u-1], c = bot[u-1];
            s1 += c - a;
            s2 += c * c - a * a;
        }
        double d1 = (double)s1, d2 = (double)s2;
        for (int off = 32; off; off >>= 1) {
            d1 += __shfl_down(d1, off);
            d2 += __shfl_down(d2, off);
        }
        if (lane == 0) { wr1[u][wv] = d1; wr2[u][wv] = d2; }
        if (x < 20)        { e1[u][x]       = s1; e2[u][x]       = s2; }
        else if (x >= 492) { e1[u][x - 472] = s1; e2[u][x - 472] = s2; }
    }
    __syncthreads();
    if (x == 0) {
        double s = 0.0;
        for (int i = 0; i < 8; ++i) s += wrT[i];
        sum1[b] = s;
    }
    if (x < NS) {
        double a = 0.0, c = 0.0;
        for (int i = 0; i < 8; ++i) { a += wr1[x][i]; c += wr2[x][i]; }
        totals1[x] = a; totals2[x] = c;
    }
    __syncthreads();
    if (x < NS * NS) {
        int u = x / NS, v = x - NS * u;
        double S1 = totals1[u], S2 = totals2[u];
        for (int j = 0; j < v; ++j)  { S1 -= (double)e1[u][j];      S2 -= (double)e2[u][j]; }
        for (int j = v; j < 20; ++j) { S1 -= (double)e1[u][20 + j]; S2 -= (double)e2[u][20 + j]; }
        const double inv = 1.0 / ((double)KWIN * (double)KWIN);
        double m1 = S1 * inv, m2 = S2 * inv;
        double var = m2 - (m1 * m1) * inv + 1e-8;   // reference's formula
        if (var < 0.0) var = 0.0;
        double tv = sum2[32] - sum1[32] * sum1[32] * (1.0 / (double)NPIX) + 1e-8;
        denom[(size_t)b * NS * NS + x] = (float)sqrt(tv * var);
    }
}

// ---------------- Kernel S: argmax + log-parabola subpixel ------------------
__global__ __launch_bounds__(64) void argmax_kernel(
    const float* __restrict__ cc, const float* __restrict__ denom,
    const double* __restrict__ sum1, float* __restrict__ shifts)
{
    int b = blockIdx.x;
    const float* C = cc    + (size_t)b * NS * NS;
    const float* D = denom + (size_t)b * NS * NS;
    float corr = (float)(sum1[b] * sum1[32] * (1.0 / (double)NPIX));
    int l = threadIdx.x;
    float best = -1e30f; int bidx = NS * NS;
    for (int i = l; i < NS * NS; i += 64) {
        float v = fabsf(C[i] - corr) / D[i];
        if (v != v) v = 0.f;               // NaN -> 0 (matches reference)
        if (v > best) { best = v; bidx = i; }
    }
    for (int off = 32; off; off >>= 1) {
        float ov = __shfl_down(best, off);
        int   oi = __shfl_down(bidx, off);
        if (ov > best || (ov == best && oi < bidx)) { best = ov; bidx = oi; }
    }
    if (l == 0) {
        int shx = bidx / NS, shy = bidx % NS;
        auto nccAt = [&](int i, int j) -> float {
            i = (i < 0) ? i + NS : i; i = (i > NS - 1) ? NS - 1 : i;  // jnp wrap-then-clamp
            j = (j < 0) ? j + NS : j; j = (j > NS - 1) ? NS - 1 : j;
            float v = fabsf(C[i * NS + j] - corr) / D[i * NS + j];
            if (v != v) v = 0.f;
            return v;
        };
        float lc  = logf(nccAt(shx, shy));
        float lxm = logf(nccAt(shx - 1, shy));
        float lxp = logf(nccAt(shx + 1, shy));
        float lym = logf(nccAt(shx, shy - 1));
        float lyp = logf(nccAt(shx, shy + 1));
        float shxn = -(float)(shx - 10) - (lxm - lxp) / (2.f * lxm - 4.f * lc + 2.f * lxp);
        float shyn = -(float)(shy - 10) - (lym - lyp) / (2.f * lym - 4.f * lc + 2.f * lyp);
        shifts[b]      = shxn;   // dy
        shifts[32 + b] = shyn;   // dx
    }
}

// ---------------- Kernel B: bilinear warp + transposed write ----------------
__device__ __forceinline__ float samp(const float* __restrict__ img, int y, int x) {
    bool valid = (y >= 0) & (y < HH) & (x >= 0) & (x < WW);
    int yc = min(max(y, 0), HH - 1), xc = min(max(x, 0), WW - 1);
    float v = img[(size_t)yc * WW + xc];
    return valid ? v : 0.f;
}

__global__ __launch_bounds__(256) void warp_kernel(
    const float* __restrict__ fr, const float* __restrict__ shifts,
    float* __restrict__ out)
{
    int b  = blockIdx.z;
    int h0 = blockIdx.y * 32;
    int w0 = blockIdx.x * 32;
    float dy = shifts[b], dx = shifts[32 + b];
    const float* img = fr + (size_t)b * NPIX;
    __shared__ float tile[32][33];
    int tx = threadIdx.x & 31;
    int tz = threadIdx.x >> 5;
#pragma unroll
    for (int s = 0; s < 4; ++s) {
        int h = h0 + tz + 8 * s;
        int w = w0 + tx;
        float yq = (float)h - dy;
        float xq = (float)w - dx;
        float y0f = floorf(yq), x0f = floorf(xq);
        float wy = yq - y0f, wx = xq - x0f;
        int y0 = (int)y0f, x0 = (int)x0f;
        float v00 = samp(img, y0,     x0);
        float v01 = samp(img, y0,     x0 + 1);
        float v10 = samp(img, y0 + 1, x0);
        float v11 = samp(img, y0 + 1, x0 + 1);
        float val = v00 * (1.f - wy) * (1.f - wx) + v01 * (1.f - wy) * wx
                  + v10 * wy * (1.f - wx)         + v11 * wy * wx;
        tile[tz + 8 * s][tx] = val;
    }
    __syncthreads();
#pragma unroll
    for (int s = 0; s < 4; ++s) {
        int hh = tx;
        int ww = tz + 8 * s;
        out[(size_t)b * NPIX + (size_t)(w0 + ww) * HH + (h0 + hh)] = tile[hh][ww];
    }
}

// ---------------- launch ----------------------------------------------------
extern "C" void kernel_launch(void* const* d_in, const int* in_sizes, int n_in,
                              void* d_out, int out_size, void* d_ws, size_t ws_size,
                              hipStream_t stream) {
    const float* fr  = (const float*)d_in[0];   // (1,32,512,512,1) flat
    const float* tpl = (const float*)d_in[1];   // (512,512)
    float* out = (float*)d_out;
    char* ws = (char*)d_ws;

    // ws layout (~43 MB)
    double* sum1    = (double*)(ws + 0);          // 33 doubles
    double* sum2    = (double*)(ws + 512);        // 33 doubles
    float*  cc      = (float*) (ws + 4096);       // 32*441 floats (zeroed)
    float*  I1      = (float*) (ws + 61440);      // 32*512 floats (zeroed)
    float*  I2      = (float*) (ws + 126976);     // 32*512 floats (zeroed)
    float*  shifts  = (float*) (ws + 196608);     // 64 floats
    float*  denom   = (float*) (ws + 200704);     // 32*441 floats
    unsigned short* frBi = (unsigned short*)(ws + 262144);    // 16.78 MB
    unsigned short* tplv = (unsigned short*)(ws + 17039360);  // 11.44 MB
    float*  part    = (float*) (ws + 28508160);   // 256*28*32*16 floats = 14.68 MB

    hipMemsetAsync(ws, 0, 192512, stream);       // zero sums + cc + I1/I2

    stage1       <<<1746, 256, 0, stream>>>(fr, tpl, frBi, tplv, I1, I2, sum1, sum2);
    corr_mfma    <<<512, 448, 0, stream>>>(frBi, tplv, part);
    reduce_stage2<<<256, 512, 0, stream>>>(part, cc, fr, I1, I2, sum1, sum2, denom);
    argmax_kernel<<<32, 64, 0, stream>>>(cc, denom, sum1, shifts);
    warp_kernel  <<<dim3(16, 16, 32), 256, 0, stream>>>(fr, shifts, out);
}